// Round 16
// baseline (509.415 us; speedup 1.0000x reference)
//
#include <hip/hip_runtime.h>
#include <hip/hip_bf16.h>

// Problem: out = lecac_linear(relu(lecac_linear(x, W1, b1)), W2, b2)
//   x: [262144, 256] f32, W1: [512,256], b1: [512], W2: [256,512], b2: [256]
// R16: R15 with ONE fix: __launch_bounds__(1024, 4). R15's spill (FETCH/WRITE
// ~1GB) was the compiler capping VGPR at 64 (default occupancy heuristic =
// 8 waves/EU) while live state needs ~120. Second arg 4 waves/EU -> 128 VGPR
// budget, 1 block/CU as designed. Everything else identical to R15:
// fused BM=64, 1024 thr, TILES=4, packed 2-bit codes in regs, v_perm unpack,
// xs double-buffered + reg prefetch, raw s_barrier + lgkmcnt only.

typedef __attribute__((ext_vector_type(8))) short bf16x8;
typedef __attribute__((ext_vector_type(4))) float f32x4;
typedef __attribute__((ext_vector_type(4))) unsigned short us4;

#define D_IN 256
#define D_HID 512
#define D_OUT 256
#define BM 64
#define TILES 4

__device__ __forceinline__ unsigned short f2bf(float f) {
  union { __hip_bfloat16 h; unsigned short u; } c;
  c.h = __float2bfloat16(f);
  return c.u;
}

__device__ __forceinline__ bf16x8 cvt8(float4 lo, float4 hi) {
  bf16x8 v;
  v[0] = (short)f2bf(lo.x); v[1] = (short)f2bf(lo.y);
  v[2] = (short)f2bf(lo.z); v[3] = (short)f2bf(lo.w);
  v[4] = (short)f2bf(hi.x); v[5] = (short)f2bf(hi.y);
  v[6] = (short)f2bf(hi.z); v[7] = (short)f2bf(hi.w);
  return v;
}

// Unpack 8 codes (half of a 16-code u32, selected by kkl) -> bf16x8.
// Code c (2 bits): 0->0.0, 1->1.0, 2->-2.0, 3->-1.0. (verified R7-R15)
__device__ __forceinline__ bf16x8 unpack8(unsigned w, int kkl) {
  unsigned te = (w >> (4 * kkl)) & 0x03030303u;        // els j = 0,2,4,6
  unsigned to = (w >> (4 * kkl + 2)) & 0x03030303u;    // els j = 1,3,5,7
  int4 o;
  unsigned s;
  s = __builtin_amdgcn_perm(to, te, 0x04040000u) + 0x00040004u;
  o.x = (int)__builtin_amdgcn_perm(0x80008000u, 0xBFC03F00u, s);
  s = __builtin_amdgcn_perm(to, te, 0x05050101u) + 0x00040004u;
  o.y = (int)__builtin_amdgcn_perm(0x80008000u, 0xBFC03F00u, s);
  s = __builtin_amdgcn_perm(to, te, 0x06060202u) + 0x00040004u;
  o.z = (int)__builtin_amdgcn_perm(0x80008000u, 0xBFC03F00u, s);
  s = __builtin_amdgcn_perm(to, te, 0x07070303u) + 0x00040004u;
  o.w = (int)__builtin_amdgcn_perm(0x80008000u, 0xBFC03F00u, s);
  return *(bf16x8*)&o;
}

// ---- prep 1: deterministic f64 partial abs-sums (8 chunks per tensor) ------
__global__ void partial_abs_kernel(const float* __restrict__ W1,
                                   const float* __restrict__ W2,
                                   double* __restrict__ part) {
  const int b = blockIdx.x;                 // 0..15
  const float* W = (b < 8) ? W1 : W2;
  const float* p = W + (b & 7) * 16384;     // 131072 / 8
  double s = 0.0;
  for (int i = threadIdx.x; i < 16384; i += 1024) s += (double)fabsf(p[i]);
  __shared__ double red[1024];
  red[threadIdx.x] = s;
  __syncthreads();
  for (int st = 512; st > 0; st >>= 1) {
    if (threadIdx.x < st) red[threadIdx.x] += red[threadIdx.x + st];
    __syncthreads();
  }
  if (threadIdx.x == 0) part[b] = red[0];
}

// ---- prep 2: pack 2-bit codes in the per-lane fragment order (1024-thr) ----
// Region 1 (W1, words 0..8191):  word = tt*8 + mf*4 + kp  (mf<2, kp<4)
//   frag row = 32*wv + 16*mf + l15,  k = (2*kp+kkl)*32 + 8*g + j
// Region 2 (W2, words 8192..16383): word = 8192 + tt*8 + kp (kp<8)
//   frag row = 16*wv + l15,  k = (2*kp+kkl)*32 + 8*g + j
// tt = thread 0..1023 (wv = tt>>6 in 0..15). Crumb (byte b, crumb c):
// j = 2b + (c&1), kkl = c>>1.
__global__ void pack_kernel(const float* __restrict__ W1,
                            const float* __restrict__ W2,
                            const double* __restrict__ part,
                            unsigned* __restrict__ pk,
                            float* __restrict__ fscales) {
  int idx = blockIdx.x * 1024 + threadIdx.x;  // 0..16383
  const double* q = part;
  double sA = 1.47 * ((((q[0]+q[1])+(q[2]+q[3]))+((q[4]+q[5])+(q[6]+q[7]))) / 131072.0) + 1e-8;
  double sB = 1.47 * ((((q[8]+q[9])+(q[10]+q[11]))+((q[12]+q[13])+(q[14]+q[15]))) / 131072.0) + 1e-8;
  if (idx == 0) { fscales[0] = (float)sA; fscales[1] = (float)sB; }
  bool is2 = idx >= 8192;
  int r = idx & 8191;
  int tt = r >> 3;                // owner thread 0..1023
  int w = r & 7;
  int wv = tt >> 6, lane = tt & 63;
  int l15 = lane & 15, g = (lane >> 4) & 3;
  unsigned word = 0;
  for (int c = 0; c < 4; ++c) {
    for (int b = 0; b < 4; ++b) {
      int j = 2 * b + (c & 1), kkl = c >> 1;
      int code;
      if (!is2) {
        int mf = w >> 2, kp = w & 3;
        int row = 32 * wv + 16 * mf + l15;
        int k = (2 * kp + kkl) * 32 + 8 * g + j;
        double v = rint((double)W1[row * 256 + k] / sA);
        code = (int)fmin(fmax(v, -2.0), 1.0) & 3;
      } else {
        int kp = w;
        int row = 16 * wv + l15;
        int k = (2 * kp + kkl) * 32 + 8 * g + j;
        double v = rint((double)W2[row * 512 + k] / sB);
        code = (int)fmin(fmax(v, -2.0), 1.0) & 3;
      }
      word |= (unsigned)code << (8 * b + 2 * c);
    }
  }
  pk[idx] = word;
}

// ---------------- fused MLP kernel ------------------------------------------
// 1024 blocks x 1024 threads (16 waves); block = 4 tiles of 64 batch rows.
// L1: wave wv owns hidden rows [32wv,32wv+32) (mf<2, nf<4, acc1 32).
// L2: wave wv owns out cols  [16wv,16wv+16) (nf<4, acc2 16).
// LDS: xs dbuf 2x32KB + hs 64KB = 128KB -> 1 block/CU; x(i+1) reg-prefetched
// during tile i (16 VGPR), staged in the epi slot. 2 raw barriers/tile.
__launch_bounds__(1024, 4)
__global__ void fused_mlp(const float* __restrict__ x,
                          const float* __restrict__ b1,
                          const float* __restrict__ b2,
                          const unsigned* __restrict__ pk,
                          const float* __restrict__ fscales,
                          float* __restrict__ out) {
  __shared__ unsigned short xs[2][BM * D_IN];  // 2 x 32 KB
  __shared__ unsigned short hs[BM * D_HID];    // 64 KB
  const int t = threadIdx.x;
  const int lane = t & 63;
  const int wv = t >> 6;       // 0..15
  const int l15 = lane & 15;
  const int g = lane >> 4;
  const long tbase = (long)blockIdx.x * TILES;
  const float s1 = fscales[0];
  const float s2 = fscales[1];
  const f32x4 zero4 = {0.f, 0.f, 0.f, 0.f};

  // ---- packed weight codes: 16 u32/thread, loaded once
  unsigned w1k[8], w2k[8];
  {
    const uint4* p1 = (const uint4*)pk + t * 2;
    const uint4* p2 = (const uint4*)(pk + 8192) + t * 2;
#pragma unroll
    for (int i = 0; i < 2; ++i) {
      uint4 a = p1[i], b = p2[i];
      w1k[4*i] = a.x; w1k[4*i+1] = a.y; w1k[4*i+2] = a.z; w1k[4*i+3] = a.w;
      w2k[4*i] = b.x; w2k[4*i+1] = b.y; w2k[4*i+2] = b.z; w2k[4*i+3] = b.w;
    }
  }

  float4 xv[4];  // next-tile x prefetch: 4 float4 = 16 VGPR

  // thread t covers 16B chunks {2t, 2t+1, 2048+2t, 2048+2t+1} of a tile
  auto loadxv = [&](long tile) {
    const float4* p = (const float4*)x + tile * 4096;
    xv[0] = p[2 * t];
    xv[1] = p[2 * t + 1];
    xv[2] = p[2048 + 2 * t];
    xv[3] = p[2049 + 2 * t];
  };
  auto stagex = [&](int buf) {  // xv -> xs[buf], swizzle slot^((m&7)<<2)
    unsigned short* xb = xs[buf];
    int m0 = t >> 5;            // chunk 2t  -> row m0 (c4 = (2t)&63)
    int sl0 = (t & 31);
    bf16x8 e0 = cvt8(xv[0], xv[1]);
    *(bf16x8*)&xb[m0 * 256 + (sl0 ^ ((m0 & 7) << 2)) * 8] = e0;
    int m1 = 32 + m0;
    bf16x8 e1 = cvt8(xv[2], xv[3]);
    *(bf16x8*)&xb[m1 * 256 + (sl0 ^ ((m1 & 7) << 2)) * 8] = e1;
  };

  f32x4 acc1[2][4];
  f32x4 acc2[4];

  // ---- prologue: stage tile 0, issue loads for tile 1
  loadxv(tbase);
  stagex(0);
  loadxv(tbase + 1);
  asm volatile("s_waitcnt lgkmcnt(0)" ::: "memory");
  __builtin_amdgcn_s_barrier();

  for (int i = 0; i < TILES; ++i) {
    // ========== L1: acc1 = W1q * xs[i&1]^T (K=256, 8 kk) ==========
    const unsigned short* xb = xs[i & 1];
#pragma unroll
    for (int a = 0; a < 2; ++a)
#pragma unroll
      for (int b = 0; b < 4; ++b) acc1[a][b] = zero4;
#pragma unroll
    for (int kp = 0; kp < 4; ++kp) {
#pragma unroll
      for (int kkl = 0; kkl < 2; ++kkl) {
        int kk = 2 * kp + kkl;
        bf16x8 bx[4];
#pragma unroll
        for (int nf = 0; nf < 4; ++nf) {
          int m = 16 * nf + l15;
          int s = (kk * 4 + g) ^ ((m & 7) << 2);
          bx[nf] = *(const bf16x8*)&xb[m * 256 + s * 8];
        }
#pragma unroll
        for (int mf = 0; mf < 2; ++mf) {
          bf16x8 fr = unpack8(w1k[mf * 4 + kp], kkl);
#pragma unroll
          for (int nf = 0; nf < 4; ++nf)
            acc1[mf][nf] = __builtin_amdgcn_mfma_f32_16x16x32_bf16(fr, bx[nf], acc1[mf][nf], 0, 0, 0);
        }
      }
    }

    // ========== epi1: hs[m][c] = relu(s1*acc1 + b1[c]), swizzled ==========
#pragma unroll
    for (int mf = 0; mf < 2; ++mf) {
      int cb = 32 * wv + 16 * mf + 4 * g;
      float4 bb = *(const float4*)&b1[cb];
      int chunk = 4 * wv + 2 * mf + (g >> 1);
      int half = (g & 1) * 4;
#pragma unroll
      for (int nf = 0; nf < 4; ++nf) {
        int m = 16 * nf + l15;
        f32x4 a = acc1[mf][nf];
        us4 o;
        o.x = f2bf(fmaxf(s1 * a[0] + bb.x, 0.f));
        o.y = f2bf(fmaxf(s1 * a[1] + bb.y, 0.f));
        o.z = f2bf(fmaxf(s1 * a[2] + bb.z, 0.f));
        o.w = f2bf(fmaxf(s1 * a[3] + bb.w, 0.f));
        int slot = chunk ^ ((m & 7) << 2);
        *(us4*)&hs[m * D_HID + slot * 8 + half] = o;
      }
    }
    if (i + 1 < TILES) stagex((i + 1) & 1);   // xv -> xs[(i+1)&1]
    if (i + 2 < TILES) loadxv(tbase + i + 2); // issue next loads (in flight)
    asm volatile("s_waitcnt lgkmcnt(0)" ::: "memory");
    __builtin_amdgcn_s_barrier();             // publish hs(i), xs[i+1]

    // ========== L2: acc2 = W2q * hs^T (K=512, 16 kk) ==========
#pragma unroll
    for (int b = 0; b < 4; ++b) acc2[b] = zero4;
#pragma unroll
    for (int kp = 0; kp < 8; ++kp) {
#pragma unroll
      for (int kkl = 0; kkl < 2; ++kkl) {
        int kk = 2 * kp + kkl;
        bf16x8 bh[4];
#pragma unroll
        for (int nf = 0; nf < 4; ++nf) {
          int m = 16 * nf + l15;
          int s = (kk * 4 + g) ^ ((m & 7) << 2);
          bh[nf] = *(const bf16x8*)&hs[m * D_HID + s * 8];
        }
        bf16x8 fr = unpack8(w2k[kp], kkl);
#pragma unroll
        for (int nf = 0; nf < 4; ++nf)
          acc2[nf] = __builtin_amdgcn_mfma_f32_16x16x32_bf16(fr, bh[nf], acc2[nf], 0, 0, 0);
      }
    }

    // ========== epi2: out stores (fire and forget) ==========
    {
      const long row0 = (tbase + i) * BM;
      int n4 = 16 * wv + 4 * g;
      float4 bb = *(const float4*)&b2[n4];
#pragma unroll
      for (int nf = 0; nf < 4; ++nf) {
        int m = 16 * nf + l15;
        f32x4 a = acc2[nf];
        float4 o;
        o.x = s2 * a[0] + bb.x;
        o.y = s2 * a[1] + bb.y;
        o.z = s2 * a[2] + bb.z;
        o.w = s2 * a[3] + bb.w;
        *(float4*)&out[(row0 + m) * D_OUT + n4] = o;
      }
    }
    asm volatile("s_waitcnt lgkmcnt(0)" ::: "memory");
    __builtin_amdgcn_s_barrier();             // hs consumed; next epi1 may write
  }
}

extern "C" void kernel_launch(void* const* d_in, const int* in_sizes, int n_in,
                              void* d_out, int out_size, void* d_ws, size_t ws_size,
                              hipStream_t stream) {
  const float* x  = (const float*)d_in[0];
  const float* W1 = (const float*)d_in[1];
  const float* b1 = (const float*)d_in[2];
  const float* W2 = (const float*)d_in[3];
  const float* b2 = (const float*)d_in[4];
  float* out = (float*)d_out;

  // ws layout: [0,128) f64 partials, [128,136) f32 scales, pk at 1024 (64 KB)
  double* part = (double*)d_ws;
  float* fsc = (float*)((char*)d_ws + 128);
  unsigned* pk = (unsigned*)((char*)d_ws + 1024);

  int Brows = in_sizes[0] / D_IN;          // 262144
  int nblk = Brows / (BM * TILES);         // 1024

  partial_abs_kernel<<<dim3(16), dim3(1024), 0, stream>>>(W1, W2, part);
  pack_kernel<<<dim3(16), dim3(1024), 0, stream>>>(W1, W2, part, pk, fsc);
  fused_mlp<<<dim3(nblk), dim3(1024), 0, stream>>>(x, b1, b2, pk, fsc, out);
}

// Round 17
// 508.251 us; speedup vs baseline: 1.0023x; 1.0023x over previous
//
#include <hip/hip_runtime.h>
#include <hip/hip_bf16.h>

// Problem: out = lecac_linear(relu(lecac_linear(x, W1, b1)), W2, b2)
//   x: [262144, 256] f32, W1: [512,256], b1: [512], W2: [256,512], b2: [256]
// R17: R15/R16 with the VGPR budget forced via the LLVM attribute
// amdgpu_waves_per_eu(4,4). R16 proved __launch_bounds__'s 2nd arg is a no-op
// here (bit-identical counters, VGPR capped at 64, ~1.7GB spill traffic =
// 100% of runtime). Live set needs ~112-125 regs; at 16 waves/block and
// 1 block/CU (128KB LDS) the feasible budget is 2048/16waves = 128/wave.
// (4,4) clamps the allocator's occupancy target to exactly 4 waves/EU.
// Everything else identical: fused BM=64, 1024 thr, TILES=4, packed 2-bit
// codes in regs, v_perm unpack, xs dbuf + reg prefetch, raw barriers.

typedef __attribute__((ext_vector_type(8))) short bf16x8;
typedef __attribute__((ext_vector_type(4))) float f32x4;
typedef __attribute__((ext_vector_type(4))) unsigned short us4;

#define D_IN 256
#define D_HID 512
#define D_OUT 256
#define BM 64
#define TILES 4

__device__ __forceinline__ unsigned short f2bf(float f) {
  union { __hip_bfloat16 h; unsigned short u; } c;
  c.h = __float2bfloat16(f);
  return c.u;
}

__device__ __forceinline__ bf16x8 cvt8(float4 lo, float4 hi) {
  bf16x8 v;
  v[0] = (short)f2bf(lo.x); v[1] = (short)f2bf(lo.y);
  v[2] = (short)f2bf(lo.z); v[3] = (short)f2bf(lo.w);
  v[4] = (short)f2bf(hi.x); v[5] = (short)f2bf(hi.y);
  v[6] = (short)f2bf(hi.z); v[7] = (short)f2bf(hi.w);
  return v;
}

// Unpack 8 codes (half of a 16-code u32, selected by kkl) -> bf16x8.
// Code c (2 bits): 0->0.0, 1->1.0, 2->-2.0, 3->-1.0. (verified R7-R16)
__device__ __forceinline__ bf16x8 unpack8(unsigned w, int kkl) {
  unsigned te = (w >> (4 * kkl)) & 0x03030303u;        // els j = 0,2,4,6
  unsigned to = (w >> (4 * kkl + 2)) & 0x03030303u;    // els j = 1,3,5,7
  int4 o;
  unsigned s;
  s = __builtin_amdgcn_perm(to, te, 0x04040000u) + 0x00040004u;
  o.x = (int)__builtin_amdgcn_perm(0x80008000u, 0xBFC03F00u, s);
  s = __builtin_amdgcn_perm(to, te, 0x05050101u) + 0x00040004u;
  o.y = (int)__builtin_amdgcn_perm(0x80008000u, 0xBFC03F00u, s);
  s = __builtin_amdgcn_perm(to, te, 0x06060202u) + 0x00040004u;
  o.z = (int)__builtin_amdgcn_perm(0x80008000u, 0xBFC03F00u, s);
  s = __builtin_amdgcn_perm(to, te, 0x07070303u) + 0x00040004u;
  o.w = (int)__builtin_amdgcn_perm(0x80008000u, 0xBFC03F00u, s);
  return *(bf16x8*)&o;
}

// ---- prep 1: deterministic f64 partial abs-sums (8 chunks per tensor) ------
__global__ void partial_abs_kernel(const float* __restrict__ W1,
                                   const float* __restrict__ W2,
                                   double* __restrict__ part) {
  const int b = blockIdx.x;                 // 0..15
  const float* W = (b < 8) ? W1 : W2;
  const float* p = W + (b & 7) * 16384;     // 131072 / 8
  double s = 0.0;
  for (int i = threadIdx.x; i < 16384; i += 1024) s += (double)fabsf(p[i]);
  __shared__ double red[1024];
  red[threadIdx.x] = s;
  __syncthreads();
  for (int st = 512; st > 0; st >>= 1) {
    if (threadIdx.x < st) red[threadIdx.x] += red[threadIdx.x + st];
    __syncthreads();
  }
  if (threadIdx.x == 0) part[b] = red[0];
}

// ---- prep 2: pack 2-bit codes in the per-lane fragment order (1024-thr) ----
// Region 1 (W1, words 0..8191):  word = tt*8 + mf*4 + kp  (mf<2, kp<4)
//   frag row = 32*wv + 16*mf + l15,  k = (2*kp+kkl)*32 + 8*g + j
// Region 2 (W2, words 8192..16383): word = 8192 + tt*8 + kp (kp<8)
//   frag row = 16*wv + l15,  k = (2*kp+kkl)*32 + 8*g + j
// tt = thread 0..1023 (wv = tt>>6 in 0..15). Crumb (byte b, crumb c):
// j = 2b + (c&1), kkl = c>>1.
__global__ void pack_kernel(const float* __restrict__ W1,
                            const float* __restrict__ W2,
                            const double* __restrict__ part,
                            unsigned* __restrict__ pk,
                            float* __restrict__ fscales) {
  int idx = blockIdx.x * 1024 + threadIdx.x;  // 0..16383
  const double* q = part;
  double sA = 1.47 * ((((q[0]+q[1])+(q[2]+q[3]))+((q[4]+q[5])+(q[6]+q[7]))) / 131072.0) + 1e-8;
  double sB = 1.47 * ((((q[8]+q[9])+(q[10]+q[11]))+((q[12]+q[13])+(q[14]+q[15]))) / 131072.0) + 1e-8;
  if (idx == 0) { fscales[0] = (float)sA; fscales[1] = (float)sB; }
  bool is2 = idx >= 8192;
  int r = idx & 8191;
  int tt = r >> 3;                // owner thread 0..1023
  int w = r & 7;
  int wv = tt >> 6, lane = tt & 63;
  int l15 = lane & 15, g = (lane >> 4) & 3;
  unsigned word = 0;
  for (int c = 0; c < 4; ++c) {
    for (int b = 0; b < 4; ++b) {
      int j = 2 * b + (c & 1), kkl = c >> 1;
      int code;
      if (!is2) {
        int mf = w >> 2, kp = w & 3;
        int row = 32 * wv + 16 * mf + l15;
        int k = (2 * kp + kkl) * 32 + 8 * g + j;
        double v = rint((double)W1[row * 256 + k] / sA);
        code = (int)fmin(fmax(v, -2.0), 1.0) & 3;
      } else {
        int kp = w;
        int row = 16 * wv + l15;
        int k = (2 * kp + kkl) * 32 + 8 * g + j;
        double v = rint((double)W2[row * 512 + k] / sB);
        code = (int)fmin(fmax(v, -2.0), 1.0) & 3;
      }
      word |= (unsigned)code << (8 * b + 2 * c);
    }
  }
  pk[idx] = word;
}

// ---------------- fused MLP kernel ------------------------------------------
// 1024 blocks x 1024 threads (16 waves); block = 4 tiles of 64 batch rows.
// L1: wave wv owns hidden rows [32wv,32wv+32) (mf<2, nf<4, acc1 32).
// L2: wave wv owns out cols  [16wv,16wv+16) (nf<4, acc2 16).
// LDS: xs dbuf 2x32KB + hs 64KB = 128KB -> 1 block/CU; x(i+1) reg-prefetched
// during tile i (16 VGPR), staged in the epi slot. 2 raw barriers/tile.
__launch_bounds__(1024)
__attribute__((amdgpu_waves_per_eu(4, 4)))
__global__ void fused_mlp(const float* __restrict__ x,
                          const float* __restrict__ b1,
                          const float* __restrict__ b2,
                          const unsigned* __restrict__ pk,
                          const float* __restrict__ fscales,
                          float* __restrict__ out) {
  __shared__ unsigned short xs[2][BM * D_IN];  // 2 x 32 KB
  __shared__ unsigned short hs[BM * D_HID];    // 64 KB
  const int t = threadIdx.x;
  const int lane = t & 63;
  const int wv = t >> 6;       // 0..15
  const int l15 = lane & 15;
  const int g = lane >> 4;
  const long tbase = (long)blockIdx.x * TILES;
  const float s1 = fscales[0];
  const float s2 = fscales[1];
  const f32x4 zero4 = {0.f, 0.f, 0.f, 0.f};

  // ---- packed weight codes: 16 u32/thread, loaded once
  unsigned w1k[8], w2k[8];
  {
    const uint4* p1 = (const uint4*)pk + t * 2;
    const uint4* p2 = (const uint4*)(pk + 8192) + t * 2;
#pragma unroll
    for (int i = 0; i < 2; ++i) {
      uint4 a = p1[i], b = p2[i];
      w1k[4*i] = a.x; w1k[4*i+1] = a.y; w1k[4*i+2] = a.z; w1k[4*i+3] = a.w;
      w2k[4*i] = b.x; w2k[4*i+1] = b.y; w2k[4*i+2] = b.z; w2k[4*i+3] = b.w;
    }
  }

  float4 xv[4];  // next-tile x prefetch: 4 float4 = 16 VGPR

  // thread t covers 16B chunks {2t, 2t+1, 2048+2t, 2048+2t+1} of a tile
  auto loadxv = [&](long tile) {
    const float4* p = (const float4*)x + tile * 4096;
    xv[0] = p[2 * t];
    xv[1] = p[2 * t + 1];
    xv[2] = p[2048 + 2 * t];
    xv[3] = p[2049 + 2 * t];
  };
  auto stagex = [&](int buf) {  // xv -> xs[buf], swizzle slot^((m&7)<<2)
    unsigned short* xb = xs[buf];
    int m0 = t >> 5;            // chunk 2t  -> row m0 (c4 = (2t)&63)
    int sl0 = (t & 31);
    bf16x8 e0 = cvt8(xv[0], xv[1]);
    *(bf16x8*)&xb[m0 * 256 + (sl0 ^ ((m0 & 7) << 2)) * 8] = e0;
    int m1 = 32 + m0;
    bf16x8 e1 = cvt8(xv[2], xv[3]);
    *(bf16x8*)&xb[m1 * 256 + (sl0 ^ ((m1 & 7) << 2)) * 8] = e1;
  };

  f32x4 acc1[2][4];
  f32x4 acc2[4];

  // ---- prologue: stage tile 0, issue loads for tile 1
  loadxv(tbase);
  stagex(0);
  loadxv(tbase + 1);
  asm volatile("s_waitcnt lgkmcnt(0)" ::: "memory");
  __builtin_amdgcn_s_barrier();

  for (int i = 0; i < TILES; ++i) {
    // ========== L1: acc1 = W1q * xs[i&1]^T (K=256, 8 kk) ==========
    const unsigned short* xb = xs[i & 1];
#pragma unroll
    for (int a = 0; a < 2; ++a)
#pragma unroll
      for (int b = 0; b < 4; ++b) acc1[a][b] = zero4;
#pragma unroll
    for (int kp = 0; kp < 4; ++kp) {
#pragma unroll
      for (int kkl = 0; kkl < 2; ++kkl) {
        int kk = 2 * kp + kkl;
        bf16x8 bx[4];
#pragma unroll
        for (int nf = 0; nf < 4; ++nf) {
          int m = 16 * nf + l15;
          int s = (kk * 4 + g) ^ ((m & 7) << 2);
          bx[nf] = *(const bf16x8*)&xb[m * 256 + s * 8];
        }
#pragma unroll
        for (int mf = 0; mf < 2; ++mf) {
          bf16x8 fr = unpack8(w1k[mf * 4 + kp], kkl);
#pragma unroll
          for (int nf = 0; nf < 4; ++nf)
            acc1[mf][nf] = __builtin_amdgcn_mfma_f32_16x16x32_bf16(fr, bx[nf], acc1[mf][nf], 0, 0, 0);
        }
      }
    }

    // ========== epi1: hs[m][c] = relu(s1*acc1 + b1[c]), swizzled ==========
#pragma unroll
    for (int mf = 0; mf < 2; ++mf) {
      int cb = 32 * wv + 16 * mf + 4 * g;
      float4 bb = *(const float4*)&b1[cb];
      int chunk = 4 * wv + 2 * mf + (g >> 1);
      int half = (g & 1) * 4;
#pragma unroll
      for (int nf = 0; nf < 4; ++nf) {
        int m = 16 * nf + l15;
        f32x4 a = acc1[mf][nf];
        us4 o;
        o.x = f2bf(fmaxf(s1 * a[0] + bb.x, 0.f));
        o.y = f2bf(fmaxf(s1 * a[1] + bb.y, 0.f));
        o.z = f2bf(fmaxf(s1 * a[2] + bb.z, 0.f));
        o.w = f2bf(fmaxf(s1 * a[3] + bb.w, 0.f));
        int slot = chunk ^ ((m & 7) << 2);
        *(us4*)&hs[m * D_HID + slot * 8 + half] = o;
      }
    }
    if (i + 1 < TILES) stagex((i + 1) & 1);   // xv -> xs[(i+1)&1]
    if (i + 2 < TILES) loadxv(tbase + i + 2); // issue next loads (in flight)
    asm volatile("s_waitcnt lgkmcnt(0)" ::: "memory");
    __builtin_amdgcn_s_barrier();             // publish hs(i), xs[i+1]

    // ========== L2: acc2 = W2q * hs^T (K=512, 16 kk) ==========
#pragma unroll
    for (int b = 0; b < 4; ++b) acc2[b] = zero4;
#pragma unroll
    for (int kp = 0; kp < 8; ++kp) {
#pragma unroll
      for (int kkl = 0; kkl < 2; ++kkl) {
        int kk = 2 * kp + kkl;
        bf16x8 bh[4];
#pragma unroll
        for (int nf = 0; nf < 4; ++nf) {
          int m = 16 * nf + l15;
          int s = (kk * 4 + g) ^ ((m & 7) << 2);
          bh[nf] = *(const bf16x8*)&hs[m * D_HID + s * 8];
        }
        bf16x8 fr = unpack8(w2k[kp], kkl);
#pragma unroll
        for (int nf = 0; nf < 4; ++nf)
          acc2[nf] = __builtin_amdgcn_mfma_f32_16x16x32_bf16(fr, bh[nf], acc2[nf], 0, 0, 0);
      }
    }

    // ========== epi2: out stores (fire and forget) ==========
    {
      const long row0 = (tbase + i) * BM;
      int n4 = 16 * wv + 4 * g;
      float4 bb = *(const float4*)&b2[n4];
#pragma unroll
      for (int nf = 0; nf < 4; ++nf) {
        int m = 16 * nf + l15;
        f32x4 a = acc2[nf];
        float4 o;
        o.x = s2 * a[0] + bb.x;
        o.y = s2 * a[1] + bb.y;
        o.z = s2 * a[2] + bb.z;
        o.w = s2 * a[3] + bb.w;
        *(float4*)&out[(row0 + m) * D_OUT + n4] = o;
      }
    }
    asm volatile("s_waitcnt lgkmcnt(0)" ::: "memory");
    __builtin_amdgcn_s_barrier();             // hs consumed; next epi1 may write
  }
}

extern "C" void kernel_launch(void* const* d_in, const int* in_sizes, int n_in,
                              void* d_out, int out_size, void* d_ws, size_t ws_size,
                              hipStream_t stream) {
  const float* x  = (const float*)d_in[0];
  const float* W1 = (const float*)d_in[1];
  const float* b1 = (const float*)d_in[2];
  const float* W2 = (const float*)d_in[3];
  const float* b2 = (const float*)d_in[4];
  float* out = (float*)d_out;

  // ws layout: [0,128) f64 partials, [128,136) f32 scales, pk at 1024 (64 KB)
  double* part = (double*)d_ws;
  float* fsc = (float*)((char*)d_ws + 128);
  unsigned* pk = (unsigned*)((char*)d_ws + 1024);

  int Brows = in_sizes[0] / D_IN;          // 262144
  int nblk = Brows / (BM * TILES);         // 1024

  partial_abs_kernel<<<dim3(16), dim3(1024), 0, stream>>>(W1, W2, part);
  pack_kernel<<<dim3(16), dim3(1024), 0, stream>>>(W1, W2, part, pk, fsc);
  fused_mlp<<<dim3(nblk), dim3(1024), 0, stream>>>(x, b1, b2, pk, fsc, out);
}

// Round 18
// 490.631 us; speedup vs baseline: 1.0383x; 1.0359x over previous
//
#include <hip/hip_runtime.h>
#include <hip/hip_bf16.h>

// Problem: out = lecac_linear(relu(lecac_linear(x, W1, b1)), W2, b2)
//   x: [262144, 256] f32, W1: [512,256], b1: [512], W2: [256,512], b2: [256]
// R18: R15's fused BM=64 pipeline at 512 THREADS. R15-R17 decoded: 1024-thr
// blocks have a hard 128-reg/wave unified budget (2048/16 waves) = 64 arch +
// 64 AGPR -> our ~112-arch live set spilled 1.7GB and no attribute can lift
// it. 512-thr blocks (8 waves/CU) get 256/wave. Wave fattens: 64 hidden rows
// (acc1 64) + 32 out cols (acc2 32) + codes 32 + xv 32 ~= 210 total, fits.
// Unpack VALU per batch-row = half of R14's. TILES=8, xs dbuf, 2 raw
// barriers/tile, x prefetched 2 tiles ahead, stores fire-and-forget.

typedef __attribute__((ext_vector_type(8))) short bf16x8;
typedef __attribute__((ext_vector_type(4))) float f32x4;
typedef __attribute__((ext_vector_type(4))) unsigned short us4;

#define D_IN 256
#define D_HID 512
#define D_OUT 256
#define BM 64
#define TILES 8

__device__ __forceinline__ unsigned short f2bf(float f) {
  union { __hip_bfloat16 h; unsigned short u; } c;
  c.h = __float2bfloat16(f);
  return c.u;
}

// Unpack 8 codes (half of a 16-code u32, selected by kkl) -> bf16x8.
// Code c (2 bits): 0->0.0, 1->1.0, 2->-2.0, 3->-1.0. (verified R7-R17)
__device__ __forceinline__ bf16x8 unpack8(unsigned w, int kkl) {
  unsigned te = (w >> (4 * kkl)) & 0x03030303u;        // els j = 0,2,4,6
  unsigned to = (w >> (4 * kkl + 2)) & 0x03030303u;    // els j = 1,3,5,7
  int4 o;
  unsigned s;
  s = __builtin_amdgcn_perm(to, te, 0x04040000u) + 0x00040004u;
  o.x = (int)__builtin_amdgcn_perm(0x80008000u, 0xBFC03F00u, s);
  s = __builtin_amdgcn_perm(to, te, 0x05050101u) + 0x00040004u;
  o.y = (int)__builtin_amdgcn_perm(0x80008000u, 0xBFC03F00u, s);
  s = __builtin_amdgcn_perm(to, te, 0x06060202u) + 0x00040004u;
  o.z = (int)__builtin_amdgcn_perm(0x80008000u, 0xBFC03F00u, s);
  s = __builtin_amdgcn_perm(to, te, 0x07070303u) + 0x00040004u;
  o.w = (int)__builtin_amdgcn_perm(0x80008000u, 0xBFC03F00u, s);
  return *(bf16x8*)&o;
}

// ---- prep 1: deterministic f64 partial abs-sums (8 chunks per tensor) ------
__global__ void partial_abs_kernel(const float* __restrict__ W1,
                                   const float* __restrict__ W2,
                                   double* __restrict__ part) {
  const int b = blockIdx.x;                 // 0..15
  const float* W = (b < 8) ? W1 : W2;
  const float* p = W + (b & 7) * 16384;     // 131072 / 8
  double s = 0.0;
  for (int i = threadIdx.x; i < 16384; i += 1024) s += (double)fabsf(p[i]);
  __shared__ double red[1024];
  red[threadIdx.x] = s;
  __syncthreads();
  for (int st = 512; st > 0; st >>= 1) {
    if (threadIdx.x < st) red[threadIdx.x] += red[threadIdx.x + st];
    __syncthreads();
  }
  if (threadIdx.x == 0) part[b] = red[0];
}

// ---- prep 2: pack 2-bit codes, per-lane fragment order (512-thr, R14) ------
// Region 1 (W1, words 0..8191):  word = tt*16 + mf*4 + kp  (mf<4, kp<4)
//   frag row = 64*wv + 16*mf + l15,  k = (2*kp+kkl)*32 + 8*g + j
// Region 2 (W2, words 8192..16383): word = 8192 + tt*16 + mf*8 + kp (mf<2,kp<8)
//   frag row = 32*wv + 16*mf + l15,  k = (2*kp+kkl)*32 + 8*g + j
// tt = thread 0..511. Crumb (byte b, crumb c): j = 2b + (c&1), kkl = c>>1.
__global__ void pack_kernel(const float* __restrict__ W1,
                            const float* __restrict__ W2,
                            const double* __restrict__ part,
                            unsigned* __restrict__ pk,
                            float* __restrict__ fscales) {
  int idx = blockIdx.x * 1024 + threadIdx.x;  // 0..16383
  const double* q = part;
  double sA = 1.47 * ((((q[0]+q[1])+(q[2]+q[3]))+((q[4]+q[5])+(q[6]+q[7]))) / 131072.0) + 1e-8;
  double sB = 1.47 * ((((q[8]+q[9])+(q[10]+q[11]))+((q[12]+q[13])+(q[14]+q[15]))) / 131072.0) + 1e-8;
  if (idx == 0) { fscales[0] = (float)sA; fscales[1] = (float)sB; }
  bool is2 = idx >= 8192;
  int r = idx & 8191;
  int tt = r >> 4;                // owner thread 0..511
  int w = r & 15;
  int wv = tt >> 6, lane = tt & 63;
  int l15 = lane & 15, g = (lane >> 4) & 3;
  unsigned word = 0;
  for (int c = 0; c < 4; ++c) {
    for (int b = 0; b < 4; ++b) {
      int j = 2 * b + (c & 1), kkl = c >> 1;
      int code;
      if (!is2) {
        int mf = w >> 2, kp = w & 3;
        int row = 64 * wv + 16 * mf + l15;
        int k = (2 * kp + kkl) * 32 + 8 * g + j;
        double v = rint((double)W1[row * 256 + k] / sA);
        code = (int)fmin(fmax(v, -2.0), 1.0) & 3;
      } else {
        int mf = w >> 3, kp = w & 7;
        int row = 32 * wv + 16 * mf + l15;
        int k = (2 * kp + kkl) * 32 + 8 * g + j;
        double v = rint((double)W2[row * 512 + k] / sB);
        code = (int)fmin(fmax(v, -2.0), 1.0) & 3;
      }
      word |= (unsigned)code << (8 * b + 2 * c);
    }
  }
  pk[idx] = word;
}

// ---------------- fused MLP kernel ------------------------------------------
// 512 blocks x 512 threads (8 waves); block = 8 tiles of 64 batch rows.
// L1: wave wv owns hidden rows [64wv,64wv+64) (mf<4, nf<4, acc1 64).
// L2: wave wv owns out cols  [32wv,32wv+32) (mf<2, nf<4, acc2 32).
// LDS: xs dbuf 2x32KB + hs 64KB = 128KB -> 1 block/CU; x(i+1) reg-prefetched
// during tile i (32 VGPR), staged in the epi slot. 2 raw barriers/tile.
__launch_bounds__(512)
__global__ void fused_mlp(const float* __restrict__ x,
                          const float* __restrict__ b1,
                          const float* __restrict__ b2,
                          const unsigned* __restrict__ pk,
                          const float* __restrict__ fscales,
                          float* __restrict__ out) {
  __shared__ unsigned short xs[2][BM * D_IN];  // 2 x 32 KB
  __shared__ unsigned short hs[BM * D_HID];    // 64 KB
  const int t = threadIdx.x;
  const int lane = t & 63;
  const int wv = t >> 6;       // 0..7
  const int l15 = lane & 15;
  const int g = lane >> 4;
  const long tbase = (long)blockIdx.x * TILES;
  const float s1 = fscales[0];
  const float s2 = fscales[1];
  const f32x4 zero4 = {0.f, 0.f, 0.f, 0.f};

  // ---- packed weight codes: 32 u32/thread, loaded once
  unsigned w1k[16], w2k[16];
  {
    const uint4* p1 = (const uint4*)pk + t * 4;
    const uint4* p2 = (const uint4*)pk + 2048 + t * 4;
#pragma unroll
    for (int i = 0; i < 4; ++i) {
      uint4 a = p1[i], b = p2[i];
      w1k[4*i] = a.x; w1k[4*i+1] = a.y; w1k[4*i+2] = a.z; w1k[4*i+3] = a.w;
      w2k[4*i] = b.x; w2k[4*i+1] = b.y; w2k[4*i+2] = b.z; w2k[4*i+3] = b.w;
    }
  }

  float4 xv[8];  // next-tile x prefetch: 8 float4 = 32 VGPR

  auto loadxv = [&](long tile) {
    const float4* p = (const float4*)x + tile * 4096;
#pragma unroll
    for (int j = 0; j < 8; ++j) xv[j] = p[j * 512 + t];
  };
  auto stagex = [&](int buf) {  // xv -> xs[buf], swizzle slot^((m&7)<<2)
    unsigned short* xb = xs[buf];
#pragma unroll
    for (int j = 0; j < 8; ++j) {
      int chunk = j * 512 + t;
      int m = chunk >> 6, c4 = chunk & 63;
      int slot = (c4 >> 1) ^ ((m & 7) << 2);
      us4 o;
      o.x = f2bf(xv[j].x); o.y = f2bf(xv[j].y);
      o.z = f2bf(xv[j].z); o.w = f2bf(xv[j].w);
      *(us4*)&xb[m * 256 + slot * 8 + (c4 & 1) * 4] = o;
    }
  };

  f32x4 acc1[4][4];
  f32x4 acc2[2][4];

  // ---- prologue: stage tile 0, issue loads for tile 1
  loadxv(tbase);
  stagex(0);
  loadxv(tbase + 1);
  asm volatile("s_waitcnt lgkmcnt(0)" ::: "memory");
  __builtin_amdgcn_s_barrier();

  for (int i = 0; i < TILES; ++i) {
    // ========== L1: acc1 = W1q * xs[i&1]^T (K=256, 8 kk) ==========
    const unsigned short* xb = xs[i & 1];
#pragma unroll
    for (int a = 0; a < 4; ++a)
#pragma unroll
      for (int b = 0; b < 4; ++b) acc1[a][b] = zero4;
#pragma unroll
    for (int kp = 0; kp < 4; ++kp) {
#pragma unroll
      for (int kkl = 0; kkl < 2; ++kkl) {
        int kk = 2 * kp + kkl;
        bf16x8 bx[4];
#pragma unroll
        for (int nf = 0; nf < 4; ++nf) {
          int m = 16 * nf + l15;
          int s = (kk * 4 + g) ^ ((m & 7) << 2);
          bx[nf] = *(const bf16x8*)&xb[m * 256 + s * 8];
        }
#pragma unroll
        for (int mf = 0; mf < 4; ++mf) {
          bf16x8 fr = unpack8(w1k[mf * 4 + kp], kkl);
#pragma unroll
          for (int nf = 0; nf < 4; ++nf)
            acc1[mf][nf] = __builtin_amdgcn_mfma_f32_16x16x32_bf16(fr, bx[nf], acc1[mf][nf], 0, 0, 0);
        }
      }
    }

    // ========== epi1: hs[m][c] = relu(s1*acc1 + b1[c]), swizzled ==========
#pragma unroll
    for (int mf = 0; mf < 4; ++mf) {
      int cb = 64 * wv + 16 * mf + 4 * g;
      float4 bb = *(const float4*)&b1[cb];
      int chunk = 8 * wv + 2 * mf + (g >> 1);
      int half = (g & 1) * 4;
#pragma unroll
      for (int nf = 0; nf < 4; ++nf) {
        int m = 16 * nf + l15;
        f32x4 a = acc1[mf][nf];
        us4 o;
        o.x = f2bf(fmaxf(s1 * a[0] + bb.x, 0.f));
        o.y = f2bf(fmaxf(s1 * a[1] + bb.y, 0.f));
        o.z = f2bf(fmaxf(s1 * a[2] + bb.z, 0.f));
        o.w = f2bf(fmaxf(s1 * a[3] + bb.w, 0.f));
        int slot = chunk ^ ((m & 7) << 2);
        *(us4*)&hs[m * D_HID + slot * 8 + half] = o;
      }
    }
    if (i + 1 < TILES) stagex((i + 1) & 1);   // xv -> xs[(i+1)&1]
    if (i + 2 < TILES) loadxv(tbase + i + 2); // issue next loads (in flight)
    asm volatile("s_waitcnt lgkmcnt(0)" ::: "memory");
    __builtin_amdgcn_s_barrier();             // publish hs(i), xs[i+1]

    // ========== L2: acc2 = W2q * hs^T (K=512, 16 kk) ==========
#pragma unroll
    for (int a = 0; a < 2; ++a)
#pragma unroll
      for (int b = 0; b < 4; ++b) acc2[a][b] = zero4;
#pragma unroll
    for (int kp = 0; kp < 8; ++kp) {
#pragma unroll
      for (int kkl = 0; kkl < 2; ++kkl) {
        int kk = 2 * kp + kkl;
        bf16x8 bh[4];
#pragma unroll
        for (int nf = 0; nf < 4; ++nf) {
          int m = 16 * nf + l15;
          int s = (kk * 4 + g) ^ ((m & 7) << 2);
          bh[nf] = *(const bf16x8*)&hs[m * D_HID + s * 8];
        }
#pragma unroll
        for (int mf = 0; mf < 2; ++mf) {
          bf16x8 fr = unpack8(w2k[mf * 8 + kp], kkl);
#pragma unroll
          for (int nf = 0; nf < 4; ++nf)
            acc2[mf][nf] = __builtin_amdgcn_mfma_f32_16x16x32_bf16(fr, bh[nf], acc2[mf][nf], 0, 0, 0);
        }
      }
    }

    // ========== epi2: out stores (fire and forget) ==========
    {
      const long row0 = (tbase + i) * BM;
#pragma unroll
      for (int mf = 0; mf < 2; ++mf) {
        int n4 = 32 * wv + 16 * mf + 4 * g;
        float4 bb = *(const float4*)&b2[n4];
#pragma unroll
        for (int nf = 0; nf < 4; ++nf) {
          int m = 16 * nf + l15;
          f32x4 a = acc2[mf][nf];
          float4 o;
          o.x = s2 * a[0] + bb.x;
          o.y = s2 * a[1] + bb.y;
          o.z = s2 * a[2] + bb.z;
          o.w = s2 * a[3] + bb.w;
          *(float4*)&out[(row0 + m) * D_OUT + n4] = o;
        }
      }
    }
    asm volatile("s_waitcnt lgkmcnt(0)" ::: "memory");
    __builtin_amdgcn_s_barrier();             // hs consumed; next epi1 may write
  }
}

extern "C" void kernel_launch(void* const* d_in, const int* in_sizes, int n_in,
                              void* d_out, int out_size, void* d_ws, size_t ws_size,
                              hipStream_t stream) {
  const float* x  = (const float*)d_in[0];
  const float* W1 = (const float*)d_in[1];
  const float* b1 = (const float*)d_in[2];
  const float* W2 = (const float*)d_in[3];
  const float* b2 = (const float*)d_in[4];
  float* out = (float*)d_out;

  // ws layout: [0,128) f64 partials, [128,136) f32 scales, pk at 1024 (64 KB)
  double* part = (double*)d_ws;
  float* fsc = (float*)((char*)d_ws + 128);
  unsigned* pk = (unsigned*)((char*)d_ws + 1024);

  int Brows = in_sizes[0] / D_IN;          // 262144
  int nblk = Brows / (BM * TILES);         // 512

  partial_abs_kernel<<<dim3(16), dim3(1024), 0, stream>>>(W1, W2, part);
  pack_kernel<<<dim3(16), dim3(1024), 0, stream>>>(W1, W2, part, pk, fsc);
  fused_mlp<<<dim3(nblk), dim3(512), 0, stream>>>(x, b1, b2, pk, fsc, out);
}

// Round 19
// 241.448 us; speedup vs baseline: 2.1098x; 2.0320x over previous
//
#include <hip/hip_runtime.h>
#include <hip/hip_bf16.h>

// Problem: out = lecac_linear(relu(lecac_linear(x, W1, b1)), W2, b2)
//   x: [262144, 256] f32, W1: [512,256], b1: [512], W2: [256,512], b2: [256]
// R19: minimal BM=64 fused kernel. R18's spill decoded: live arch (codes 32 +
// xv 32 + frags + staging ~136) > the allocator's 128 cap (it targets 2
// blocks/CU, ignoring LDS). Fix: (a) drop the xv register prefetch and the
// xs double-buffer entirely (R14's direct stage was clean), (b) alias xs into
// hs -> 64KB LDS -> 2 blocks/CU, (c) request the true occupancy via
// amdgpu_waves_per_eu(2,2)+flat_work_group_size INSTEAD of launch_bounds
// (R17 evidence: launch_bounds overrides the attribute). BM=64 halves the
// dominant unpack-VALU stream vs R14 (VALUBusy 66% -> ~45%).

typedef __attribute__((ext_vector_type(8))) short bf16x8;
typedef __attribute__((ext_vector_type(4))) float f32x4;
typedef __attribute__((ext_vector_type(4))) unsigned short us4;

#define D_IN 256
#define D_HID 512
#define D_OUT 256
#define BM 64

__device__ __forceinline__ unsigned short f2bf(float f) {
  union { __hip_bfloat16 h; unsigned short u; } c;
  c.h = __float2bfloat16(f);
  return c.u;
}

// Unpack 8 codes (half of a 16-code u32, selected by kkl) -> bf16x8.
// Code c (2 bits): 0->0.0, 1->1.0, 2->-2.0, 3->-1.0. (verified R7-R18)
__device__ __forceinline__ bf16x8 unpack8(unsigned w, int kkl) {
  unsigned te = (w >> (4 * kkl)) & 0x03030303u;        // els j = 0,2,4,6
  unsigned to = (w >> (4 * kkl + 2)) & 0x03030303u;    // els j = 1,3,5,7
  int4 o;
  unsigned s;
  s = __builtin_amdgcn_perm(to, te, 0x04040000u) + 0x00040004u;
  o.x = (int)__builtin_amdgcn_perm(0x80008000u, 0xBFC03F00u, s);
  s = __builtin_amdgcn_perm(to, te, 0x05050101u) + 0x00040004u;
  o.y = (int)__builtin_amdgcn_perm(0x80008000u, 0xBFC03F00u, s);
  s = __builtin_amdgcn_perm(to, te, 0x06060202u) + 0x00040004u;
  o.z = (int)__builtin_amdgcn_perm(0x80008000u, 0xBFC03F00u, s);
  s = __builtin_amdgcn_perm(to, te, 0x07070303u) + 0x00040004u;
  o.w = (int)__builtin_amdgcn_perm(0x80008000u, 0xBFC03F00u, s);
  return *(bf16x8*)&o;
}

// ---- prep 1: deterministic f64 partial abs-sums (8 chunks per tensor) ------
__global__ void partial_abs_kernel(const float* __restrict__ W1,
                                   const float* __restrict__ W2,
                                   double* __restrict__ part) {
  const int b = blockIdx.x;                 // 0..15
  const float* W = (b < 8) ? W1 : W2;
  const float* p = W + (b & 7) * 16384;     // 131072 / 8
  double s = 0.0;
  for (int i = threadIdx.x; i < 16384; i += 1024) s += (double)fabsf(p[i]);
  __shared__ double red[1024];
  red[threadIdx.x] = s;
  __syncthreads();
  for (int st = 512; st > 0; st >>= 1) {
    if (threadIdx.x < st) red[threadIdx.x] += red[threadIdx.x + st];
    __syncthreads();
  }
  if (threadIdx.x == 0) part[b] = red[0];
}

// ---- prep 2: pack 2-bit codes, per-lane fragment order (512-thr) -----------
// Region 1 (W1, words 0..8191):  word = tt*16 + mf*4 + kp  (mf<4, kp<4)
//   frag row = 64*wv + 16*mf + l15,  k = (2*kp+kkl)*32 + 8*g + j
// Region 2 (W2, words 8192..16383): word = 8192 + tt*16 + mf*8 + kp (mf<2,kp<8)
//   frag row = 32*wv + 16*mf + l15,  k = (2*kp+kkl)*32 + 8*g + j
// tt = thread 0..511. Crumb (byte b, crumb c): j = 2b + (c&1), kkl = c>>1.
__global__ void pack_kernel(const float* __restrict__ W1,
                            const float* __restrict__ W2,
                            const double* __restrict__ part,
                            unsigned* __restrict__ pk,
                            float* __restrict__ fscales) {
  int idx = blockIdx.x * 1024 + threadIdx.x;  // 0..16383
  const double* q = part;
  double sA = 1.47 * ((((q[0]+q[1])+(q[2]+q[3]))+((q[4]+q[5])+(q[6]+q[7]))) / 131072.0) + 1e-8;
  double sB = 1.47 * ((((q[8]+q[9])+(q[10]+q[11]))+((q[12]+q[13])+(q[14]+q[15]))) / 131072.0) + 1e-8;
  if (idx == 0) { fscales[0] = (float)sA; fscales[1] = (float)sB; }
  bool is2 = idx >= 8192;
  int r = idx & 8191;
  int tt = r >> 4;                // owner thread 0..511
  int w = r & 15;
  int wv = tt >> 6, lane = tt & 63;
  int l15 = lane & 15, g = (lane >> 4) & 3;
  unsigned word = 0;
  for (int c = 0; c < 4; ++c) {
    for (int b = 0; b < 4; ++b) {
      int j = 2 * b + (c & 1), kkl = c >> 1;
      int code;
      if (!is2) {
        int mf = w >> 2, kp = w & 3;
        int row = 64 * wv + 16 * mf + l15;
        int k = (2 * kp + kkl) * 32 + 8 * g + j;
        double v = rint((double)W1[row * 256 + k] / sA);
        code = (int)fmin(fmax(v, -2.0), 1.0) & 3;
      } else {
        int mf = w >> 3, kp = w & 7;
        int row = 32 * wv + 16 * mf + l15;
        int k = (2 * kp + kkl) * 32 + 8 * g + j;
        double v = rint((double)W2[row * 512 + k] / sB);
        code = (int)fmin(fmax(v, -2.0), 1.0) & 3;
      }
      word |= (unsigned)code << (8 * b + 2 * c);
    }
  }
  pk[idx] = word;
}

// ---------------- fused MLP kernel ------------------------------------------
// 4096 blocks x 512 threads (8 waves); block = one 64-batch-row tile.
// L1: wave wv owns hidden rows [64wv,64wv+64) (mf<4, nf<4, acc1 64 AGPR).
// L2: wave wv owns out cols  [32wv,32wv+32) (mf<2, nf<4, acc2 32 AGPR).
// LDS: hs 64KB, xs aliases its first 32KB -> 2 blocks/CU (if regs permit).
// stage -> sync -> L1 -> sync -> epi1 -> sync -> L2 -> stores.
__attribute__((amdgpu_flat_work_group_size(512, 512), amdgpu_waves_per_eu(2, 2)))
__global__ void fused_mlp(const float* __restrict__ x,
                          const float* __restrict__ b1,
                          const float* __restrict__ b2,
                          const unsigned* __restrict__ pk,
                          const float* __restrict__ fscales,
                          float* __restrict__ out) {
  __shared__ unsigned short hs[BM * D_HID];    // 64 KB
  unsigned short* xs = hs;                     // x tile aliases first 32 KB
  const int t = threadIdx.x;
  const int lane = t & 63;
  const int wv = t >> 6;       // 0..7
  const int l15 = lane & 15;
  const int g = lane >> 4;
  const long row0 = (long)blockIdx.x * BM;
  const float s1 = fscales[0];
  const float s2 = fscales[1];
  const f32x4 zero4 = {0.f, 0.f, 0.f, 0.f};

  // ---- packed weight codes: 32 u32/thread, loaded once (pk L2-resident)
  unsigned w1k[16], w2k[16];
  {
    const uint4* p1 = (const uint4*)pk + t * 4;
    const uint4* p2 = (const uint4*)pk + 2048 + t * 4;
#pragma unroll
    for (int i = 0; i < 4; ++i) {
      uint4 a = p1[i], b = p2[i];
      w1k[4*i] = a.x; w1k[4*i+1] = a.y; w1k[4*i+2] = a.z; w1k[4*i+3] = a.w;
      w2k[4*i] = b.x; w2k[4*i+1] = b.y; w2k[4*i+2] = b.z; w2k[4*i+3] = b.w;
    }
  }

  // ---- stage x tile: [64][256] f32 -> bf16, swizzle slot^((m&7)<<2)
  {
    const float4* p = (const float4*)(x + row0 * D_IN);
#pragma unroll
    for (int j = 0; j < 8; ++j) {
      int chunk = j * 512 + t;        // 4096 float4 chunks, coalesced
      int m = chunk >> 6, c4 = chunk & 63;
      float4 v = p[chunk];
      int slot = (c4 >> 1) ^ ((m & 7) << 2);
      us4 o;
      o.x = f2bf(v.x); o.y = f2bf(v.y); o.z = f2bf(v.z); o.w = f2bf(v.w);
      *(us4*)&xs[m * 256 + slot * 8 + (c4 & 1) * 4] = o;
    }
  }
  __syncthreads();

  // ========== L1: acc1 = W1q * xs^T (K=256, 8 kk) ==========
  f32x4 acc1[4][4];
#pragma unroll
  for (int a = 0; a < 4; ++a)
#pragma unroll
    for (int b = 0; b < 4; ++b) acc1[a][b] = zero4;
#pragma unroll
  for (int kp = 0; kp < 4; ++kp) {
#pragma unroll
    for (int kkl = 0; kkl < 2; ++kkl) {
      int kk = 2 * kp + kkl;
      bf16x8 bx[4];
#pragma unroll
      for (int nf = 0; nf < 4; ++nf) {
        int m = 16 * nf + l15;
        int s = (kk * 4 + g) ^ ((m & 7) << 2);
        bx[nf] = *(const bf16x8*)&xs[m * 256 + s * 8];
      }
#pragma unroll
      for (int mf = 0; mf < 4; ++mf) {
        bf16x8 fr = unpack8(w1k[mf * 4 + kp], kkl);
#pragma unroll
        for (int nf = 0; nf < 4; ++nf)
          acc1[mf][nf] = __builtin_amdgcn_mfma_f32_16x16x32_bf16(fr, bx[nf], acc1[mf][nf], 0, 0, 0);
      }
    }
  }
  __syncthreads();   // all xs reads done; hs (aliased) may be overwritten

  // ========== epi1: hs[m][c] = relu(s1*acc1 + b1[c]), swizzled ==========
#pragma unroll
  for (int mf = 0; mf < 4; ++mf) {
    int cb = 64 * wv + 16 * mf + 4 * g;
    float4 bb = *(const float4*)&b1[cb];
    int chunk = 8 * wv + 2 * mf + (g >> 1);
    int half = (g & 1) * 4;
#pragma unroll
    for (int nf = 0; nf < 4; ++nf) {
      int m = 16 * nf + l15;
      f32x4 a = acc1[mf][nf];
      us4 o;
      o.x = f2bf(fmaxf(s1 * a[0] + bb.x, 0.f));
      o.y = f2bf(fmaxf(s1 * a[1] + bb.y, 0.f));
      o.z = f2bf(fmaxf(s1 * a[2] + bb.z, 0.f));
      o.w = f2bf(fmaxf(s1 * a[3] + bb.w, 0.f));
      int slot = chunk ^ ((m & 7) << 2);
      *(us4*)&hs[m * D_HID + slot * 8 + half] = o;
    }
  }
  __syncthreads();   // hs published

  // ========== L2: acc2 = W2q * hs^T (K=512, 16 kk) ==========
  f32x4 acc2[2][4];
#pragma unroll
  for (int a = 0; a < 2; ++a)
#pragma unroll
    for (int b = 0; b < 4; ++b) acc2[a][b] = zero4;
#pragma unroll
  for (int kp = 0; kp < 8; ++kp) {
#pragma unroll
    for (int kkl = 0; kkl < 2; ++kkl) {
      int kk = 2 * kp + kkl;
      bf16x8 bh[4];
#pragma unroll
      for (int nf = 0; nf < 4; ++nf) {
        int m = 16 * nf + l15;
        int s = (kk * 4 + g) ^ ((m & 7) << 2);
        bh[nf] = *(const bf16x8*)&hs[m * D_HID + s * 8];
      }
#pragma unroll
      for (int mf = 0; mf < 2; ++mf) {
        bf16x8 fr = unpack8(w2k[mf * 8 + kp], kkl);
#pragma unroll
        for (int nf = 0; nf < 4; ++nf)
          acc2[mf][nf] = __builtin_amdgcn_mfma_f32_16x16x32_bf16(fr, bh[nf], acc2[mf][nf], 0, 0, 0);
      }
    }
  }

  // ========== epi2: out[m][n] = s2*acc2 + b2[n], float4 stores ==========
#pragma unroll
  for (int mf = 0; mf < 2; ++mf) {
    int n4 = 32 * wv + 16 * mf + 4 * g;
    float4 bb = *(const float4*)&b2[n4];
#pragma unroll
    for (int nf = 0; nf < 4; ++nf) {
      int m = 16 * nf + l15;
      f32x4 a = acc2[mf][nf];
      float4 o;
      o.x = s2 * a[0] + bb.x;
      o.y = s2 * a[1] + bb.y;
      o.z = s2 * a[2] + bb.z;
      o.w = s2 * a[3] + bb.w;
      *(float4*)&out[(row0 + m) * D_OUT + n4] = o;
    }
  }
}

extern "C" void kernel_launch(void* const* d_in, const int* in_sizes, int n_in,
                              void* d_out, int out_size, void* d_ws, size_t ws_size,
                              hipStream_t stream) {
  const float* x  = (const float*)d_in[0];
  const float* W1 = (const float*)d_in[1];
  const float* b1 = (const float*)d_in[2];
  const float* W2 = (const float*)d_in[3];
  const float* b2 = (const float*)d_in[4];
  float* out = (float*)d_out;

  // ws layout: [0,128) f64 partials, [128,136) f32 scales, pk at 1024 (64 KB)
  double* part = (double*)d_ws;
  float* fsc = (float*)((char*)d_ws + 128);
  unsigned* pk = (unsigned*)((char*)d_ws + 1024);

  int Brows = in_sizes[0] / D_IN;     // 262144
  int nblk = Brows / BM;              // 4096

  partial_abs_kernel<<<dim3(16), dim3(1024), 0, stream>>>(W1, W2, part);
  pack_kernel<<<dim3(16), dim3(1024), 0, stream>>>(W1, W2, part, pk, fsc);
  fused_mlp<<<dim3(nblk), dim3(512), 0, stream>>>(x, b1, b2, pk, fsc, out);
}